// Round 6
// baseline (349.557 us; speedup 1.0000x reference)
//
#include <hip/hip_runtime.h>
#include <math.h>

#define TPB 64   // one wave per block; one block per row

// Packed complex: clang ext_vector_type(2) float -> VOP3P v_pk_{add,mul,fma}_f32
typedef float cplx __attribute__((ext_vector_type(2)));

__device__ __forceinline__ cplx cmul(cplx a, cplx b) {
    return a.xx * b + cplx{-a.y, a.y} * b.yx;
}

__device__ __forceinline__ void dft4(cplx& a, cplx& b, cplx& c, cplx& d) {
    cplx t0 = a + c, t1 = a - c, t2 = b + d, t3 = b - d;
    a = t0 + t2;
    c = t0 - t2;
    cplx jt3 = cplx{t3.y, -t3.x};   // -i * t3
    b = t1 + jt3;
    d = t1 - jt3;
}

// 16-point DFT; input v[l] natural, output bin m at v[T16(m)].
#define T16(j) (4 * ((j) & 3) + ((j) >> 2))
// 64-point DFT; input v[n] natural, output bin k at v[R64(k)].
#define R64(k) (16 * ((k) & 3) + T16((k) >> 2))

__device__ __forceinline__ void dft16(cplx* v) {
#pragma unroll
    for (int j = 0; j < 4; ++j) dft4(v[j], v[4 + j], v[8 + j], v[12 + j]);
    const float C1 = 0.9238795325112867f, S1 = 0.3826834323650898f;
    const float R2 = 0.7071067811865476f;
    v[5]  = cmul(v[5],  cplx{ C1, -S1});
    v[9]  = cmul(v[9],  cplx{ R2, -R2});
    v[13] = cmul(v[13], cplx{ S1, -C1});
    v[6]  = cmul(v[6],  cplx{ R2, -R2});
    v[10] = cplx{v[10].y, -v[10].x};
    v[14] = cmul(v[14], cplx{-R2, -R2});
    v[7]  = cmul(v[7],  cplx{ S1, -C1});
    v[11] = cmul(v[11], cplx{-R2, -R2});
    v[15] = cmul(v[15], cplx{-C1,  S1});
#pragma unroll
    for (int b = 0; b < 4; ++b) dft4(v[4 * b], v[4 * b + 1], v[4 * b + 2], v[4 * b + 3]);
}

// e^{-i pi n/32} = (W64C[n], -W64S[n]); true cos/sin values.
__device__ constexpr float W64C[48] = {
    1.f, 0.9951847267f, 0.9807852804f, 0.9569403357f, 0.9238795325f, 0.8819212643f,
    0.8314696123f, 0.7730104534f, 0.7071067812f, 0.6343932842f, 0.5555702330f,
    0.4713967368f, 0.3826834324f, 0.2902846773f, 0.1950903220f, 0.0980171403f,
    0.f, -0.0980171403f, -0.1950903220f, -0.2902846773f, -0.3826834324f,
    -0.4713967368f, -0.5555702330f, -0.6343932842f, -0.7071067812f, -0.7730104534f,
    -0.8314696123f, -0.8819212643f, -0.9238795325f, -0.9569403357f, -0.9807852804f,
    -0.9951847267f, -1.f, -0.9951847267f, -0.9807852804f, -0.9569403357f,
    -0.9238795325f, -0.8819212643f, -0.8314696123f, -0.7730104534f, -0.7071067812f,
    -0.6343932842f, -0.5555702330f, -0.4713967368f, -0.3826834324f, -0.2902846773f,
    -0.1950903220f, -0.0980171403f};
__device__ constexpr float W64S[48] = {
    0.f, 0.0980171403f, 0.1950903220f, 0.2902846773f, 0.3826834324f, 0.4713967368f,
    0.5555702330f, 0.6343932842f, 0.7071067812f, 0.7730104534f, 0.8314696123f,
    0.8819212643f, 0.9238795325f, 0.9569403357f, 0.9807852804f, 0.9951847267f,
    1.f, 0.9951847267f, 0.9807852804f, 0.9569403357f, 0.9238795325f, 0.8819212643f,
    0.8314696123f, 0.7730104534f, 0.7071067812f, 0.6343932842f, 0.5555702330f,
    0.4713967368f, 0.3826834324f, 0.2902846773f, 0.1950903220f, 0.0980171403f,
    0.f, -0.0980171403f, -0.1950903220f, -0.2902846773f, -0.3826834324f,
    -0.4713967368f, -0.5555702330f, -0.6343932842f, -0.7071067812f, -0.7730104534f,
    -0.8314696123f, -0.8819212643f, -0.9238795325f, -0.9569403357f, -0.9807852804f,
    -0.9951847267f};

// e^{-i pi p/64}: true cos/sin, p=0..32.
__device__ constexpr float W128C[33] = {
    1.f, 0.9987954562f, 0.9951847267f, 0.9891765100f, 0.9807852804f, 0.9700312532f,
    0.9569403357f, 0.9415440652f, 0.9238795325f, 0.9039892931f, 0.8819212643f,
    0.8577286100f, 0.8314696123f, 0.8032075315f, 0.7730104534f, 0.7409511254f,
    0.7071067812f, 0.6715589548f, 0.6343932842f, 0.5956993045f, 0.5555702330f,
    0.5141027442f, 0.4713967368f, 0.4275550934f, 0.3826834324f, 0.3368898534f,
    0.2902846773f, 0.2429801799f, 0.1950903220f, 0.1467304745f, 0.0980171403f,
    0.0490676743f, 0.f};
__device__ constexpr float W128S[33] = {
    0.f, 0.0490676743f, 0.0980171403f, 0.1467304745f, 0.1950903220f, 0.2429801799f,
    0.2902846773f, 0.3368898534f, 0.3826834324f, 0.4275550934f, 0.4713967368f,
    0.5141027442f, 0.5555702330f, 0.5956993045f, 0.6343932842f, 0.6715589548f,
    0.7071067812f, 0.7409511254f, 0.7730104534f, 0.8032075315f, 0.8314696123f,
    0.8577286100f, 0.8819212643f, 0.9039892931f, 0.9238795325f, 0.9415440652f,
    0.9569403357f, 0.9700312532f, 0.9807852804f, 0.9891765100f, 0.9951847267f,
    0.9987954562f, 1.f};

// In-register 64-pt DFT: 16x dft4 (stride-16 groups) -> w64^{js} twiddles
// (all literal) -> 4x dft16 on contiguous 16s. X[s+4q] lands at v[16s+T16(q)].
__device__ __forceinline__ void dft64(cplx v[64]) {
#pragma unroll
    for (int j = 0; j < 16; ++j) dft4(v[j], v[j + 16], v[j + 32], v[j + 48]);
#pragma unroll
    for (int s = 1; s < 4; ++s) {
#pragma unroll
        for (int j = 1; j < 16; ++j) {
            const int n = j * s;
            v[j + 16 * s] = cmul(v[j + 16 * s], cplx{W64C[n], -W64S[n]});
        }
    }
#pragma unroll
    for (int s = 0; s < 4; ++s) dft16(v + 16 * s);
}

// R0-R5 post-mortem: six structurally different 256-thread barrier-phase
// kernels all land 68-87us while VALU-issue ~22us, HBM-floor ~21us, LDS ~12us.
// The invariant is the 8-segment barrier-lockstep chain. This version removes
// it: 4096 = 64x64, ONE WAVE per row, zero s_barriers. Per-lane dft64 ->
// lane twiddle -> wave-private 32KB LDS transpose (lgkmcnt-only sync) ->
// per-lane dft64 -> split with __shfl partner exchange. 5 blocks/CU (LDS).
__global__ __launch_bounds__(TPB, 2) void snr_kernel(const float* __restrict__ x,
                                                     const float* __restrict__ targets,
                                                     float* __restrict__ out,
                                                     float* __restrict__ ws) {
    __shared__ __align__(16) cplx W[4096];   // 32 KB, private to this wave
    float* zf = (float*)W;                   // cap slots [0..5], free post-transpose

    const int l = threadIdx.x;               // lane 0..63
    const int bid = blockIdx.x;              // row index

    // ---- load: v[j] = x_cplx[l + 64j]; lane-major => fully coalesced b64 ----
    cplx v[64];
    const cplx* row = (const cplx*)(x + (size_t)bid * 8192);
#pragma unroll
    for (int j = 0; j < 64; ++j) v[j] = row[l + (j << 6)];

    // ---- r (uniform): argmin |i*df - tg| ----
    int r;
    {
        float tg = targets[bid];
        const float df = 0.00244140625f;  // 10/4096 exact
        int c0 = (int)(tg * 409.6f) - 2;
        if (c0 < 0) c0 = 0;
        r = c0;
        float best = fabsf(df * (float)c0 - tg);
        for (int i = c0 + 1; i <= c0 + 4 && i <= 4096; ++i) {
            float dd = fabsf(df * (float)i - tg);
            if (dd < best) { best = dd; r = i; }  // strict <: first-min == argmin
        }
    }
    const int r2 = 2 * r;

    // ---- p-mask for cap bins landing in p in [27,32] (uniform) ----
    unsigned long long pm = 0;
    {
        int capb[6] = {r - 1, r, r + 1, r2 - 1, r2, r2 + 1};
#pragma unroll
        for (int i = 0; i < 6; ++i) {
            int c = capb[i];
            int kk = (c <= 2048) ? c : 4096 - c;
            pm |= 1ull << (kk >> 6);
        }
    }

    // ---- inner DFT over j: y_l[q] = sum_j v[j] w64^{jq}, at v[R64(q)] ----
    dft64(v);

    // ---- lane twiddle tables: w4096^{l*q} = wB[q>>3] * wA[q&7] ----
    cplx wA[8], wB[8];
    {
        float sn, cs;
        __sincosf(-1.5339807878856412e-3f * (float)l, &sn, &cs);  // -2pi/4096*l
        cplx w1 = cplx{cs, sn};
        wA[0] = cplx{1.f, 0.f};
#pragma unroll
        for (int b = 1; b < 8; ++b) wA[b] = cmul(wA[b - 1], w1);
        cplx w8 = cmul(wA[7], w1);
        wB[0] = cplx{1.f, 0.f};
#pragma unroll
        for (int a = 1; a < 8; ++a) wB[a] = cmul(wB[a - 1], w8);
    }

    // ---- transpose write (lane twiddle fused): logical (l,q) -> rotated phys
    //      ((l+q)&63) + 64q: every b64 access hits each bank exactly 4x = min ----
#pragma unroll
    for (int q = 0; q < 64; ++q) {
        cplx val = v[R64(q)];
        if (q != 0) {
            cplx tw = (q < 8) ? wA[q]
                      : (((q & 7) == 0) ? wB[q >> 3] : cmul(wB[q >> 3], wA[q & 7]));
            val = cmul(val, tw);
        }
        W[((l + q) & 63) + (q << 6)] = val;
    }
    // wave-synchronous: no s_barrier, just drain this wave's ds ops
    asm volatile("s_waitcnt lgkmcnt(0)" ::: "memory");
#pragma unroll
    for (int j = 0; j < 64; ++j) v[j] = W[((j + l) & 63) + (l << 6)];

    // ---- outer DFT over source lane j: X[l + 64p] at v[R64(p)] ----
    dft64(v);

    // ---- rfft split: X[k]=0.5[(Zk+conj(Zn)) - i w^k (Zk-conj(Zn))], Zn at
    //      partner lane 64-l, reg R64(63-p). Band [273,1706] = p 4..26 edges. ----
    float band = 0.f;
    cplx wl;
    {
        float sn, cs;
        __sincosf(-7.669903939428206e-4f * (float)l, &sn, &cs);  // -pi/4096*l
        wl = cplx{cs, sn};
    }
    const int plane = (64 - l) & 63;
#pragma unroll
    for (int p = 4; p <= 32; ++p) {
        if (p > 26 && !((pm >> p) & 1)) continue;   // uniform skip (caps only)
        cplx Zk = v[R64(p)];
        cplx Zn;
        Zn.x = __shfl(v[R64(63 - p)].x, plane);
        Zn.y = __shfl(v[R64(63 - p)].y, plane);
        if (l == 0) Zn = v[R64((64 - p) & 63)];     // lane0 self-pairs: reg 64-p
        cplx wk = cmul(wl, cplx{W128C[p], -W128S[p]});
        cplx Znc = cplx{Zn.x, -Zn.y};
        cplx s  = Zk + Znc;
        cplx dd = Zk - Znc;
        cplx tt = cmul(wk, dd);
        cplx Xk = s + cplx{tt.y, -tt.x};            // 2*X[k]
        float Pk = (Xk.x * Xk.x + Xk.y * Xk.y) * (1.0f / 32768.0f);
        if (p >= 5 && p <= 25) band += Pk;
        else if (p == 4)  { if (l >= 17) band += Pk; }   // k=256+l >= 273
        else if (p == 26) { if (l <= 42) band += Pk; }   // k=1664+l <= 1706
        const int k = l + (p << 6);
        int d1 = k - (r - 1);  if ((unsigned)d1 < 3u) zf[d1] = Pk;
        int d2 = k - (r2 - 1); if ((unsigned)d2 < 3u) zf[3 + d2] = Pk;
        cplx Xn = s + cplx{-tt.y, tt.x};            // 2*conj(X[4096-k])
        float Pn = (Xn.x * Xn.x + Xn.y * Xn.y) * (1.0f / 32768.0f);
        int e2 = (4096 - k) - (r2 - 1); if ((unsigned)e2 < 3u) zf[3 + e2] = Pn;
    }

    // ---- wave reduce band; caps via wave-local LDS (no cross-wave races) ----
#pragma unroll
    for (int off = 32; off > 0; off >>= 1) band += __shfl_down(band, off);

    asm volatile("s_waitcnt lgkmcnt(0)" ::: "memory");
    unsigned c = 0;
    if (l == 0) {
        float S = zf[1] + zf[4] + 0.5f * (zf[0] + zf[2]);
        float noise = band;
        if (r <= 1706)      noise -= zf[1];
        if (r - 1 >= 273)   noise -= 0.5f * zf[0];
        if (r + 1 <= 1706)  noise -= 0.5f * zf[2];
        if (r2 - 1 <= 1706) noise -= zf[3];
        if (r2 <= 1706)     noise -= zf[4];
        if (r2 + 1 <= 1706) noise -= zf[5];
        float loss = -10.0f * log10f(S / (noise + 1.0f));
        // 64-slot spread: 4096 same-address atomics would serialize at L2
        atomicAdd(&ws[bid & 63], loss * (1.0f / 4096.0f));
        __threadfence();
        c = atomicAdd((unsigned*)(ws + 64), 1u) + 1;
    }
    c = __shfl(c, 0);
    if (c == (unsigned)gridDim.x) {   // last block: fold the 64 partials
        __threadfence();
        float sv = ws[l];
#pragma unroll
        for (int off = 32; off > 0; off >>= 1) sv += __shfl_down(sv, off);
        if (l == 0) out[0] = sv;
    }
}

extern "C" void kernel_launch(void* const* d_in, const int* in_sizes, int n_in,
                              void* d_out, int out_size, void* d_ws, size_t ws_size,
                              hipStream_t stream) {
    const float* x = (const float*)d_in[0];    // outputs: (4096, 8192) fp32
    const float* tg = (const float*)d_in[1];   // targets: (4096, 1) fp32
    float* out = (float*)d_out;                // scalar fp32
    float* ws = (float*)d_ws;                  // 64 partials + 1 counter
    hipMemsetAsync(ws, 0, 65 * sizeof(float), stream);
    snr_kernel<<<4096, TPB, 0, stream>>>(x, tg, out, ws);
}

// Round 7
// 201.191 us; speedup vs baseline: 1.7374x; 1.7374x over previous
//
#include <hip/hip_runtime.h>
#include <math.h>

#define TPB 256
#define ROWS 4   // grid 1024; 2 blocks/CU resident (64 KB LDS each)

// Packed complex: clang ext_vector_type(2) float -> VOP3P v_pk_{add,mul,fma}_f32
typedef float cplx __attribute__((ext_vector_type(2)));

typedef const __attribute__((address_space(1))) char gchar_t;  // global
typedef __attribute__((address_space(3))) char lchar_t;        // LDS

__device__ __forceinline__ cplx cmul(cplx a, cplx b) {
    return a.xx * b + cplx{-a.y, a.y} * b.yx;
}

__device__ __forceinline__ void dft4(cplx& a, cplx& b, cplx& c, cplx& d) {
    cplx t0 = a + c, t1 = a - c, t2 = b + d, t3 = b - d;
    a = t0 + t2;
    c = t0 - t2;
    cplx jt3 = cplx{t3.y, -t3.x};   // -i * t3
    b = t1 + jt3;
    d = t1 - jt3;
}

// In-register 16-point DFT. Input v[l]; output y[m] lands at v[T16(m)].
#define T16(j) (4 * ((j) & 3) + ((j) >> 2))

__device__ __forceinline__ void dft16(cplx v[16]) {
#pragma unroll
    for (int j = 0; j < 4; ++j) dft4(v[j], v[4 + j], v[8 + j], v[12 + j]);
    const float C1 = 0.9238795325112867f, S1 = 0.3826834323650898f;
    const float R2 = 0.7071067811865476f;
    v[5]  = cmul(v[5],  cplx{ C1, -S1});
    v[9]  = cmul(v[9],  cplx{ R2, -R2});
    v[13] = cmul(v[13], cplx{ S1, -C1});
    v[6]  = cmul(v[6],  cplx{ R2, -R2});
    v[10] = cplx{v[10].y, -v[10].x};
    v[14] = cmul(v[14], cplx{-R2, -R2});
    v[7]  = cmul(v[7],  cplx{ S1, -C1});
    v[11] = cmul(v[11], cplx{-R2, -R2});
    v[15] = cmul(v[15], cplx{-C1,  S1});
#pragma unroll
    for (int b = 0; b < 4; ++b) dft4(v[4 * b], v[4 * b + 1], v[4 * b + 2], v[4 * b + 3]);
}

// LDS-only barrier: orders ds ops WITHOUT draining vmcnt -> the next-row
// global_load_lds DMA stays in flight across the FFT's internal exchanges.
__device__ __forceinline__ void bar_lds() {
    asm volatile("s_waitcnt lgkmcnt(0)" ::: "memory");
    __builtin_amdgcn_s_barrier();
    asm volatile("" ::: "memory");
}

// DMA one 32 KB row into LDS staging: 8 calls/thread, 16 B/lane.
__device__ __forceinline__ void dma_row(const float* rowp, char* ldsbase,
                                        int wid, int lane) {
    const char* g = (const char*)rowp + wid * 8192 + lane * 16;
    char* l = ldsbase + wid * 8192;
#pragma unroll
    for (int j = 0; j < 8; ++j) {
        __builtin_amdgcn_global_load_lds((gchar_t*)(g + j * 1024),
                                         (lchar_t*)(l + j * 1024), 16, 0, 0);
    }
}

// R6 post-mortem: wave-autonomous (1 wave/row, 0 barriers) -> occupancy 10%,
// dur 203us: latency exposure beats barrier removal. R5 structure retained;
// this round deletes its export+split+caps LDS tail (3 segments) by remapping
// stage-2's logical column t' so conjugate partners (t', 256-t') sit at lanes
// l, l^32 of the SAME wave: split partners come from __shfl_xor(.,32), caps
// are computed by owner lanes in the same m-loop, zf moves to a separate tiny
// LDS array (no overlay barrier). 7 barriers/row -> 4.
__global__ __launch_bounds__(TPB, 2) void snr_kernel(const float* __restrict__ x,
                                                     const float* __restrict__ targets,
                                                     float* __restrict__ out) {
    __shared__ __align__(16) cplx A[4096];   // 32 KB staging (linear row image)
    __shared__ __align__(16) cplx B[4096];   // 32 KB exchange
    __shared__ float zfs[16];                // caps [0..5], wave partials [8..11]

    const int t = threadIdx.x;
    const int tl = t & 15;
    const int rb = t ^ ((t >> 4) & 15);   // phys base for logical slots t+256l
    const int wbase = t << 4;
    const int row0 = blockIdx.x * ROWS;
    const int wid = t >> 6, lane = t & 63;

    // ---- stage-2 logical column sigma(w,l): partner 256-t' at lane l^32 ----
    int tp = (lane < 32) ? (32 * wid + 1 + lane) : (287 - 32 * wid - lane);
    if (t == 255) tp = 0;                   // bijection fix-up
    const bool self128 = (t == 223);        // tp==128: self-paired
    const bool self0   = (t == 255);        // tp==0:   self-paired
    const int rb2 = tp ^ ((tp >> 4) & 15);  // phys base for slots tp+256l

    // ---- hoisted twiddles (row-invariant; VGPRs free at 2 blocks/CU) ----
    cplx tw0[16], tw1[16], wl;
    {
        float ang = -1.5339807878856412e-3f * (float)t;  // -2pi/4096 * t
        float sn, cs; __sincosf(ang, &sn, &cs);
        cplx w1 = cplx{cs, sn};
        cplx u2 = cmul(w1, w1), u3 = cmul(u2, w1);
        cplx v4 = cmul(u2, u2), v8 = cmul(v4, v4), v12 = cmul(v8, v4);
        cplx ua[4] = {cplx{1.f, 0.f}, w1, u2, u3};
        cplx vb[4] = {cplx{1.f, 0.f}, v4, v8, v12};
#pragma unroll
        for (int m = 0; m < 16; ++m) tw0[m] = cmul(vb[m >> 2], ua[m & 3]);
    }
    {
        float ang = -0.02454369260617026f * (float)(t >> 4);  // -2pi/256 * p
        float sn, cs; __sincosf(ang, &sn, &cs);
        cplx w1 = cplx{cs, sn};
        cplx u2 = cmul(w1, w1), u3 = cmul(u2, w1);
        cplx v4 = cmul(u2, u2), v8 = cmul(v4, v4), v12 = cmul(v8, v4);
        cplx ua[4] = {cplx{1.f, 0.f}, w1, u2, u3};
        cplx vb[4] = {cplx{1.f, 0.f}, v4, v8, v12};
#pragma unroll
        for (int m = 0; m < 16; ++m) tw1[m] = cmul(vb[m >> 2], ua[m & 3]);
    }
    {
        float ang = -7.669903939428206e-4f * (float)tp;  // -pi/4096 * t'
        float sn, cs; __sincosf(ang, &sn, &cs);
        wl = cplx{cs, sn};
    }

    // e^{-i pi m/16} tables, m=0..13 (literal)
    const float WMc[14] = {1.f, 0.9807852804f, 0.9238795325f, 0.8314696123f,
                           0.7071067812f, 0.5555702330f, 0.3826834324f,
                           0.1950903220f, 0.f, -0.1950903220f, -0.3826834324f,
                           -0.5555702330f, -0.7071067812f, -0.8314696123f};
    const float WMs[14] = {0.f, 0.1950903220f, 0.3826834324f, 0.5555702330f,
                           0.7071067812f, 0.8314696123f, 0.9238795325f,
                           0.9807852804f, 1.f, 0.9807852804f, 0.9238795325f,
                           0.8314696123f, 0.7071067812f, 0.5555702330f};

    // ---- prologue: DMA row0 into A; full drain ----
    dma_row(x + (size_t)row0 * 8192, (char*)A, wid, lane);
    __syncthreads();

    float lossSum = 0.f;

#pragma unroll 1
    for (int it = 0; it < ROWS; ++it) {
        cplx a[16];
#pragma unroll
        for (int l = 0; l < 16; ++l) a[l] = A[t + 256 * l];

        // ---- r (uniform per row) ----
        int r;
        {
            float tg = targets[row0 + it];
            const float df = 0.00244140625f;  // 10/4096 exact
            int c0 = (int)(tg * 409.6f) - 2;
            if (c0 < 0) c0 = 0;
            r = c0;
            float best = fabsf(df * (float)c0 - tg);
            for (int i = c0 + 1; i <= c0 + 4 && i <= 4096; ++i) {
                float dd = fabsf(df * (float)i - tg);
                if (dd < best) { best = dd; r = i; }  // strict <: argmin ties
            }
        }
        // cap ownership: group1 bins r-1+dA (dA<3), group2 bins 2r-1+dB
        int mA = -1, slotA = 0, mB = -1, slotB = 0;
        {
            int dA = (tp - (r - 1)) & 255;
            if (dA < 3) { slotA = dA; mA = (r - 1 + dA) >> 8; }
            int dB = (tp - (2 * r - 1)) & 255;
            if (dB < 3) { slotB = 3 + dB; mB = (2 * r - 1 + dB) >> 8; }
        }

        // ======== stage 0: dest g = 16t + m ========
        dft16(a);
#pragma unroll
        for (int m = 1; m < 16; ++m) { int j = T16(m); a[j] = cmul(a[j], tw0[m]); }
#pragma unroll
        for (int j = 0; j < 16; ++j) B[wbase + (T16(j) ^ tl)] = a[j];
        bar_lds();   // (1) all waves' A-reads also retired -> A is free

        if (it + 1 < ROWS) dma_row(x + (size_t)(row0 + it + 1) * 8192, (char*)A, wid, lane);

        // ======== stage 1 ========
#pragma unroll
        for (int l = 0; l < 16; ++l) a[l] = B[rb + (l << 8)];
        bar_lds();   // (2) in-place exchange: reads before writes
        dft16(a);
#pragma unroll
        for (int m = 1; m < 16; ++m) { int j = T16(m); a[j] = cmul(a[j], tw1[m]); }
        {
            const int base1 = (t >> 4) << 8;
#pragma unroll
            for (int m = 0; m < 16; ++m) B[base1 + (m << 4) + (tl ^ m)] = a[T16(m)];
        }
        bar_lds();   // (3)

        // ======== stage 2 on logical column t' ========
#pragma unroll
        for (int l = 0; l < 16; ++l) a[l] = B[rb2 + (l << 8)];
        dft16(a);
        // a[T16(q)] = Z4096 bin (tp + 256q)

        // ---- partner values via in-wave register exchange ----
        cplx sw[15];
#pragma unroll
        for (int j = 2; j <= 14; ++j) {
            sw[j].x = __shfl_xor(a[T16(j)].x, 32);
            sw[j].y = __shfl_xor(a[T16(j)].y, 32);
        }

        // ======== rfft split: band (m 1..6) + caps (m 1..13), one loop ========
        float band = 0.f, capA = 0.f, capB = 0.f;
#pragma unroll
        for (int m = 1; m <= 13; ++m) {
            cplx Zk = a[T16(m)];
            cplx Zn = sw[15 - m];                       // partner's T16(15-m)
            if (self128) Zn = a[T16(15 - m)];           // tp=128 self-pairs
            if (self0)   Zn = a[T16((16 - m) & 15)];    // tp=0   self-pairs
            cplx Znc = cplx{Zn.x, -Zn.y};
            cplx s  = Zk + Znc;
            cplx dd = Zk - Znc;
            cplx wk = cmul(wl, cplx{WMc[m], -WMs[m]});  // e^{-i pi k/4096}
            cplx tt = cmul(wk, dd);
            cplx X  = s + cplx{tt.y, -tt.x};            // 2*X[k]
            float P = (X.x * X.x + X.y * X.y) * (1.0f / 32768.0f);
            if (m >= 2 && m <= 5) band += P;
            else if (m == 1) { if (tp >= 17)  band += P; }   // k=tp+256 >= 273
            else if (m == 6) { if (tp <= 170) band += P; }   // k=tp+1536 <= 1706
            if (m == mA) capA = P;
            if (m == mB) capB = P;
        }
        if (mA >= 0) zfs[slotA] = capA;   // unique owner lane per cap bin
        if (mB >= 0) zfs[slotB] = capB;

        // ---- block reduce band ----
#pragma unroll
        for (int off = 32; off > 0; off >>= 1) band += __shfl_down(band, off);
        if (lane == 0) zfs[8 + wid] = band;

        // (4) FULL sync: drains vmcnt (next-row DMA complete), zfs visible,
        // and all stage-2 B-reads retired before next row's stage-0 B-writes.
        __syncthreads();

        if (t == 0) {
            float bb = zfs[8] + zfs[9] + zfs[10] + zfs[11];
            float S = zfs[1] + zfs[4] + 0.5f * (zfs[0] + zfs[2]);
            float noise = bb;
            const int r2 = 2 * r;
            if (r <= 1706)      noise -= zfs[1];
            if (r - 1 >= 273)   noise -= 0.5f * zfs[0];
            if (r + 1 <= 1706)  noise -= 0.5f * zfs[2];
            if (r2 - 1 <= 1706) noise -= zfs[3];
            if (r2 <= 1706)     noise -= zfs[4];
            if (r2 + 1 <= 1706) noise -= zfs[5];
            lossSum += -10.0f * log10f(S / (noise + 1.0f));
        }
    }

    if (t == 0) atomicAdd(out, lossSum * (1.0f / 4096.0f));
}

extern "C" void kernel_launch(void* const* d_in, const int* in_sizes, int n_in,
                              void* d_out, int out_size, void* d_ws, size_t ws_size,
                              hipStream_t stream) {
    const float* x = (const float*)d_in[0];    // outputs: (4096, 8192) fp32
    const float* tg = (const float*)d_in[1];   // targets: (4096, 1) fp32
    float* out = (float*)d_out;                // scalar fp32
    hipMemsetAsync(out, 0, sizeof(float), stream);
    snr_kernel<<<4096 / ROWS, TPB, 0, stream>>>(x, tg, out);
}